// Round 9
// baseline (3642.012 us; speedup 1.0000x reference)
//
#include <hip/hip_runtime.h>
#include <math.h>

// DNC forward v9: R8 flags/dep-graph, role C compressed from ~18 barrier
// phases to 6 wide phases with wave-group concurrency (wc/rcs softmax fully
// in-wave, fwd/bwd overlapped with rcs, mnorm fused into rcs loads). Role A
// posts fA right after h0new; outproj finish moved off the critical path.

#define TT   64
#define BB   32
#define INW  64
#define OUTW 64
#define NN   128
#define WD   64
#define RR   4
#define HH   256
#define IFSZ 471
#define CLIPV 20.0f
#define EPSV  1e-6f
#define NBLK 96

// interface vector offsets
#define OFF_RK   0
#define OFF_RSTR 256
#define OFF_WK   260
#define OFF_WSTR 324
#define OFF_ER   325
#define OFF_WV   389
#define OFF_FG   453
#define OFF_AG   457
#define OFF_WG   458
#define OFF_MD   459

// scal slots
#define S_AG   1
#define S_WG   2
#define S_WSUM 4
#define S_BM   20
#define S_FM   24
#define S_CM   28

// ---- LDS layouts (floats) ----
#define A_XS   0
#define A_GL   11840
#define A_C0   12896
#define A_GO   13152
#define A_WS   13216
#define A_WO   34528
#define B_XS   0
#define B_GL   9472
#define B_C1   10528
#define B_W1   10784
#define C_MS   0
#define C_LS   8320
#define C_WW   24832
#define C_PRC  24960
#define C_USG  25088
#define C_RWS  25216
#define C_IFC  25728
#define C_FWD  26208    // also part[1024] for IF matvec
#define C_BWD  26720
#define C_U2   27232
#define C_WCS  27360
#define C_RCS  27488    // also ctl_l[256] staging for IF
#define C_MNO  28000
#define C_ERS  28384
#define C_WVS  28448
#define C_SCAL 28576

#define SMEM_FLOATS 36064
#define SMEM_BYTES  (SMEM_FLOATS*4)

// ---- ws layout (floats) ----
#define W_CTL  0       // [256][32]
#define W_RDS  8192    // [256][32]
#define W_H0   16384   // [2][256*32]
#define W_H1   32768   // [2][256*32]
#define W_FLA  49152
#define W_FLB  (W_FLA + 1024)
#define W_FLC  (W_FLB + 1024)
#define W_END  (W_FLC + 1024)

__device__ __forceinline__ float sigf(float x){ return 1.0f/(1.0f+expf(-x)); }
__device__ __forceinline__ float sofp(float x){ return fmaxf(x,0.0f)+log1pf(expf(-fabsf(x))); }

__device__ __forceinline__ float gload(const float* p){
  return __hip_atomic_load(p, __ATOMIC_RELAXED, __HIP_MEMORY_SCOPE_AGENT);
}
__device__ __forceinline__ void gstore(float* p, float v){
  __hip_atomic_store(p, v, __ATOMIC_RELAXED, __HIP_MEMORY_SCOPE_AGENT);
}

__device__ __forceinline__ void waitflag(const unsigned* slots, unsigned target){
  if (threadIdx.x < 64){
    for (;;){
      unsigned m = __hip_atomic_load(&slots[(threadIdx.x & 31)*32],
                                     __ATOMIC_RELAXED, __HIP_MEMORY_SCOPE_AGENT);
      #pragma unroll
      for (int s=32;s>0;s>>=1){
        unsigned o = (unsigned)__shfl_xor((int)m, s, 64);
        m = (o < m) ? o : m;
      }
      if (m >= target) break;
      __builtin_amdgcn_s_sleep(2);
    }
  }
  __syncthreads();
}

__device__ __forceinline__ void setflag(unsigned* slots, int g, unsigned val){
  asm volatile("s_waitcnt vmcnt(0)" ::: "memory");
  __syncthreads();
  if (threadIdx.x == 0)
    __hip_atomic_store(&slots[g*32], val, __ATOMIC_RELAXED, __HIP_MEMORY_SCOPE_AGENT);
}

__device__ __forceinline__ float wmax64(float v){
  #pragma unroll
  for (int m=32;m>0;m>>=1) v = fmaxf(v, __shfl_xor(v,m,64));
  return v;
}
__device__ __forceinline__ float wsum64(float v){
  #pragma unroll
  for (int m=32;m>0;m>>=1) v += __shfl_xor(v,m,64);
  return v;
}

// 6-stage butterfly reduce-scatter over 64 lanes
__device__ __forceinline__ float bfly64(float (&A)[64], int l, int* jb){
  #pragma unroll
  for (int st=0; st<6; ++st){
    const int m = 1<<st, half = 32>>st;
    const bool hi = (l & m) != 0;
    #pragma unroll
    for (int j=0;j<half;j++){
      float a = A[j], b = A[j+half];
      float keep = hi? b : a;
      float send = hi? a : b;
      A[j] = keep + __shfl_xor(send, m, 64);
    }
  }
  *jb = ((l&1)?32:0)|((l&2)?16:0)|((l&4)?8:0)|((l&8)?4:0)|((l&16)?2:0)|((l&32)?1:0);
  return A[0];
}

#define TILE_FMA(WBASE, WROW, XROW)                                      \
  {                                                                      \
    float xv[8], wv[8];                                                  \
    _Pragma("unroll")                                                    \
    for (int q=0;q<8;q++){                                               \
      wv[q] = sm[(WBASE) + (WROW)*37 + c0 + q];                          \
      xv[q] = Xs[(XROW)*37 + b0 + q];                                    \
    }                                                                    \
    _Pragma("unroll")                                                    \
    for (int bi=0;bi<8;bi++)                                             \
      _Pragma("unroll")                                                  \
      for (int ci=0;ci<8;ci++)                                           \
        acc[bi*8+ci] += xv[bi]*wv[ci];                                   \
  }

extern "C" __global__ __launch_bounds__(1024, 1)
void dnc_coop9(const float* __restrict__ inputs,
               const float* __restrict__ Wx0, const float* __restrict__ Wh0, const float* __restrict__ b0g,
               const float* __restrict__ Wx1, const float* __restrict__ Wh1, const float* __restrict__ b1g,
               const float* __restrict__ Wifg, const float* __restrict__ bifg,
               const float* __restrict__ Woutg, const float* __restrict__ boutg,
               float* __restrict__ outg, float* __restrict__ ws)
{
  const int bid  = blockIdx.x;
  const int role = bid >> 5;
  const int g    = bid & 31;
  const int tid  = threadIdx.x;
  const int lane = tid & 63;
  const int wid  = tid >> 6;

  extern __shared__ float sm[];

  float* gctl  = ws + W_CTL;
  float* greads= ws + W_RDS;
  unsigned* fA = (unsigned*)(ws + W_FLA);
  unsigned* fB = (unsigned*)(ws + W_FLB);
  unsigned* fC = (unsigned*)(ws + W_FLC);

  // ---- one-time weight staging + state init ----
  if (role == 0){
    for (int i = tid; i < 576*32; i += 1024){
      int r = i >> 5, cl = i & 31;
      int cglob = 8*g + (cl&7) + ((cl>>3)<<8);
      float v;
      if (r < 256)      v = Wx0[(64+r)*1024 + cglob];
      else if (r < 320) v = Wx0[(r-256)*1024 + cglob];
      else              v = Wh0[(r-320)*1024 + cglob];
      sm[A_WS + r*37 + cl] = v;
    }
    for (int i = tid; i < 512*2; i += 1024){
      int k = i >> 1, c = i & 1;
      sm[A_WO + k*3 + c] = Woutg[k*64 + 2*g + c];
    }
    if (tid < 256) sm[A_C0 + tid] = 0.0f;
  } else if (role == 1){
    for (int i = tid; i < 512*32; i += 1024){
      int r = i >> 5, cl = i & 31;
      int cglob = 8*g + (cl&7) + ((cl>>3)<<8);
      sm[B_W1 + r*37 + cl] = (r < 256) ? Wx1[r*1024 + cglob]
                                       : Wh1[(r-256)*1024 + cglob];
    }
    if (tid < 256) sm[B_C1 + tid] = 0.0f;
  } else {
    for (int i = tid; i < NN*65;  i += 1024) sm[C_MS + i] = 0.0f;
    for (int i = tid; i < NN*129; i += 1024) sm[C_LS + i] = 0.0f;
    if (tid < 128){ sm[C_WW+tid]=0.f; sm[C_PRC+tid]=0.f; sm[C_USG+tid]=0.f; }
    if (tid < 512) sm[C_RWS+tid]=0.f;
  }
  __syncthreads();

  if (role == 0){
    // =================== ROLE A ===================
    float* Xs = sm + A_XS;
    for (int t = 0; t <= TT; ++t){
      float* h0old = ws + W_H0 + (t&1)*8192;
      float* h0new = ws + W_H0 + ((t+1)&1)*8192;
      float acc[64]; float accO[16];

      waitflag(fA, (unsigned)t);
      if (t < TT){
        for (int i = tid; i < 256*32; i += 1024){
          int k = i>>5, bb = i&31; Xs[k*37+bb] = gload(&h0old[i]);
        }
        for (int i = tid; i < 64*32; i += 1024){
          int bb = i>>6, k = i&63;
          Xs[(256+k)*37+bb] = inputs[(t*BB + bb)*INW + k];
        }
        __syncthreads();
        #pragma unroll
        for (int j=0;j<64;j++) acc[j]=0.f;
        {
          const int b0 = (wid>>2)*8, c0 = (wid&3)*8;
          #pragma unroll
          for (int i=0;i<4;i++){
            int k = i*64 + lane;
            TILE_FMA(A_WS, 320+k, k)          // Wh0 @ h0old
          }
          TILE_FMA(A_WS, 256+lane, 256+lane)  // Wx(x) @ x_t
        }
        __syncthreads();
      }
      if (t > 0){
        waitflag(fB, (unsigned)t);
        for (int i = tid; i < 256*32; i += 1024){
          int k = i>>5, bb = i&31; Xs[k*37+bb] = gload(&gctl[i]);
        }
        __syncthreads();
        #pragma unroll
        for (int j=0;j<16;j++) accO[j]=0.f;
        if (wid < 4){
          const int b0 = wid*8;
          #pragma unroll
          for (int i=0;i<4;i++){
            int k = i*64 + lane;
            float w0 = sm[A_WO + k*3], w1 = sm[A_WO + k*3 + 1];
            float xv[8];
            #pragma unroll
            for (int q=0;q<8;q++) xv[q] = Xs[k*37 + b0 + q];
            #pragma unroll
            for (int bi=0;bi<8;bi++){
              accO[bi*2]   += xv[bi]*w0;
              accO[bi*2+1] += xv[bi]*w1;
            }
          }
        }
        __syncthreads();
      }
      // --- critical path: reads(t-1) ---
      waitflag(fC, (unsigned)t);
      for (int i = tid; i < 256*32; i += 1024){
        int k = i>>5, bb = i&31; Xs[k*37+bb] = gload(&greads[i]);
      }
      __syncthreads();
      if (t < TT){
        {
          const int b0 = (wid>>2)*8, c0 = (wid&3)*8;
          #pragma unroll
          for (int i=0;i<4;i++){
            int k = i*64 + lane;
            TILE_FMA(A_WS, k, k)              // Wx(reads) @ reads
          }
          int jb; float v = bfly64(acc, lane, &jb);
          sm[A_GL + (b0 + (jb>>3))*33 + c0 + (jb&7)] = v;
        }
        __syncthreads();
        if (tid < 256){
          int bb = tid>>3, j = tid&7;
          float gi = sm[A_GL + bb*33 + j]      + b0g[8*g + j];
          float gf = sm[A_GL + bb*33 + 8 + j]  + b0g[256 + 8*g + j];
          float gg = sm[A_GL + bb*33 + 16 + j] + b0g[512 + 8*g + j];
          float go = sm[A_GL + bb*33 + 24 + j] + b0g[768 + 8*g + j];
          float c = sigf(gf)*sm[A_C0+tid] + sigf(gi)*tanhf(gg);
          sm[A_C0+tid] = c;
          gstore(&h0new[(8*g + j)*32 + bb], sigf(go)*tanhf(c));
        }
        setflag(fA, g, (unsigned)(t+1));   // unblock B ASAP
      }
      // --- off-critical: finish outproj(t-1) ---
      if (t > 0){
        if (wid < 4){
          const int b0 = wid*8;
          #pragma unroll
          for (int i=0;i<4;i++){
            int k = i*64 + lane;
            float w0 = sm[A_WO + (256+k)*3], w1 = sm[A_WO + (256+k)*3 + 1];
            float xv[8];
            #pragma unroll
            for (int q=0;q<8;q++) xv[q] = Xs[k*37 + b0 + q];
            #pragma unroll
            for (int bi=0;bi<8;bi++){
              accO[bi*2]   += xv[bi]*w0;
              accO[bi*2+1] += xv[bi]*w1;
            }
          }
          #pragma unroll
          for (int st=0; st<4; ++st){
            const int m = 1<<st, half = 8>>st;
            const bool hi = (lane & m) != 0;
            #pragma unroll
            for (int j=0;j<half;j++){
              float a = accO[j], b = accO[j+half];
              float keep = hi? b : a;
              float send = hi? a : b;
              accO[j] = keep + __shfl_xor(send, m, 64);
            }
          }
          accO[0] += __shfl_xor(accO[0], 16, 64);
          accO[0] += __shfl_xor(accO[0], 32, 64);
          int jb = ((lane&1)?8:0)|((lane&2)?4:0)|((lane&4)?2:0)|((lane&8)?1:0);
          if ((lane & 48) == 0){
            int bi = jb>>1, ci = jb&1;
            sm[A_GO + (wid*8+bi)*2 + ci] = accO[0];
          }
        }
        __syncthreads();
        if (tid < 64){
          int bb = tid>>1, c = tid&1;
          float v = sm[A_GO + tid] + boutg[2*g + c];
          outg[((t-1)*BB + bb)*OUTW + 2*g + c] = fminf(CLIPV, fmaxf(-CLIPV, v));
        }
      }
    }
  } else if (role == 1){
    // =================== ROLE B ===================
    float* Xs = sm + B_XS;
    for (int t = 0; t < TT; ++t){
      float* h0new = ws + W_H0 + ((t+1)&1)*8192;
      float* h1old = ws + W_H1 + (t&1)*8192;
      float* h1new = ws + W_H1 + ((t+1)&1)*8192;
      float acc[64];
      #pragma unroll
      for (int j=0;j<64;j++) acc[j]=0.f;

      waitflag(fB, (unsigned)t);
      for (int i = tid; i < 256*32; i += 1024){
        int k = i>>5, bb = i&31; Xs[k*37+bb] = gload(&h1old[i]);
      }
      __syncthreads();
      {
        const int b0 = (wid>>2)*8, c0 = (wid&3)*8;
        #pragma unroll
        for (int i=0;i<4;i++){
          int k = i*64 + lane;
          TILE_FMA(B_W1, 256+k, k)
        }
      }
      __syncthreads();
      waitflag(fA, (unsigned)(t+1));
      for (int i = tid; i < 256*32; i += 1024){
        int k = i>>5, bb = i&31; Xs[k*37+bb] = gload(&h0new[i]);
      }
      __syncthreads();
      {
        const int b0 = (wid>>2)*8, c0 = (wid&3)*8;
        #pragma unroll
        for (int i=0;i<4;i++){
          int k = i*64 + lane;
          TILE_FMA(B_W1, k, k)
        }
        int jb; float v = bfly64(acc, lane, &jb);
        sm[B_GL + (b0 + (jb>>3))*33 + c0 + (jb&7)] = v;
      }
      __syncthreads();
      if (tid < 256){
        int bb = tid>>3, j = tid&7;
        float gi = sm[B_GL + bb*33 + j]      + b1g[8*g + j];
        float gf = sm[B_GL + bb*33 + 8 + j]  + b1g[256 + 8*g + j];
        float gg = sm[B_GL + bb*33 + 16 + j] + b1g[512 + 8*g + j];
        float go = sm[B_GL + bb*33 + 24 + j] + b1g[768 + 8*g + j];
        float c = sigf(gf)*sm[B_C1+tid] + sigf(gi)*tanhf(gg);
        sm[B_C1+tid] = c;
        float h = sigf(go)*tanhf(c);
        gstore(&h1new[(8*g + j)*32 + bb], h);
        gstore(&gctl[(8*g + j)*32 + bb], fminf(CLIPV, fmaxf(-CLIPV, h)));
      }
      setflag(fB, g, (unsigned)(t+1));
    }
  } else {
    // =================== ROLE C: compressed memory module ===================
    float* Ms  = sm + C_MS;
    float* Ls  = sm + C_LS;
    float* wws = sm + C_WW;
    float* prc = sm + C_PRC;
    float* usg = sm + C_USG;
    float* rws = sm + C_RWS;
    float* ifcl= sm + C_IFC;
    float* fwds= sm + C_FWD;
    float* bwds= sm + C_BWD;
    float* u2  = sm + C_U2;
    float* wcs = sm + C_WCS;
    float* rcs = sm + C_RCS;
    float* mno = sm + C_MNO;
    float* ers = sm + C_ERS;
    float* wvs = sm + C_WVS;
    float* scal= sm + C_SCAL;
    float* ctl_l = sm + C_RCS;   // overlay (rcs written later)
    float* part  = sm + C_FWD;   // overlay [1024] (fwd/bwd written later)

    for (int t = 0; t < TT; ++t){
      // idle: ||M(t-1)|| for wc
      if (tid < 128){
        float s=0.f;
        #pragma unroll 8
        for (int d=0;d<WD;d++){ float v=Ms[tid*65+d]; s+=v*v; }
        mno[tid]=sqrtf(s);
      }
      waitflag(fB, (unsigned)(t+1));
      if (tid < 256) ctl_l[tid] = gload(&gctl[tid*32 + g]);
      __syncthreads();
      {
        const int kq = tid >> 9, c = tid & 511;
        if (c < IFSZ){
          const float* Wp = Wifg + (size_t)(kq*128)*IFSZ + c;
          const float* xp = ctl_l + kq*128;
          float a0=0.f, a1=0.f;
          #pragma unroll 8
          for (int k=0;k<128;k+=2){
            a0 += xp[k]   * Wp[(size_t)k*IFSZ];
            a1 += xp[k+1] * Wp[(size_t)(k+1)*IFSZ];
          }
          part[kq*512 + c] = a0 + a1;
        }
      }
      __syncthreads();
      if (tid < IFSZ) ifcl[tid] = part[tid] + part[512+tid] + bifg[tid];
      __syncthreads();

      // ---- C1: wc softmax (w0) ∥ gates/modes (w1) ∥ usage (w2-3) ∥ ers/wvs (w4) ----
      if (wid == 0){
        int n1 = lane, n2 = lane + 64;
        float d1=0.f, d2=0.f, kn=0.f;
        #pragma unroll 8
        for (int d=0; d<WD; ++d){
          float wk = ifcl[OFF_WK+d];
          d1 += wk*Ms[n1*65+d];
          d2 += wk*Ms[n2*65+d];
          kn += wk*wk;
        }
        float wstr = 1.0f + sofp(ifcl[OFF_WSTR]);
        float knr = sqrtf(kn);
        float s1 = d1/(knr*mno[n1]+EPSV)*wstr;
        float s2 = d2/(knr*mno[n2]+EPSV)*wstr;
        float mx = wmax64(fmaxf(s1,s2));
        float e1 = expf(s1-mx), e2 = expf(s2-mx);
        float sum = wsum64(e1+e2);
        wcs[n1] = e1/sum; wcs[n2] = e2/sum;
      } else if (wid == 1){
        if (lane < 4){
          float m0=ifcl[OFF_MD+lane*3], m1=ifcl[OFF_MD+lane*3+1], m2=ifcl[OFF_MD+lane*3+2];
          float mx=fmaxf(m0,fmaxf(m1,m2));
          float e0=expf(m0-mx), e1=expf(m1-mx), e2=expf(m2-mx);
          float s=e0+e1+e2;
          scal[S_BM+lane]=e0/s; scal[S_FM+lane]=e1/s; scal[S_CM+lane]=e2/s;
        }
        if (lane == 4) scal[S_AG]=sigf(ifcl[OFF_AG]);
        if (lane == 5) scal[S_WG]=sigf(ifcl[OFF_WG]);
      } else if (wid == 2 || wid == 3){
        int n = tid - 128;
        float cw = wws[n];
        float u  = usg[n] + (1.0f-usg[n])*cw;
        float psi = 1.0f;
        #pragma unroll
        for (int r=0;r<RR;r++) psi *= 1.0f - sigf(ifcl[OFF_FG+r])*rws[r*NN+n];
        float us = u*psi;
        usg[n] = us;
        u2[n]  = EPSV + (1.0f-EPSV)*us;
      } else if (wid == 4){
        ers[lane] = sigf(ifcl[OFF_ER+lane]);
        wvs[lane] = ifcl[OFF_WV+lane];
      }
      __syncthreads();

      // ---- C2: allocation + ww + wsum, wave 0 (2 slots/lane, in-wave) ----
      if (wid == 0){
        int n1 = lane, n2 = lane + 64;
        float uA = u2[n1], uB = u2[n2];
        float p1 = 1.0f, p2 = 1.0f;
        for (int j=0;j<NN;j++){
          float uj = u2[j];
          p1 *= ((uj<uA)||(uj==uA && j<n1)) ? uj : 1.0f;
          p2 *= ((uj<uB)||(uj==uB && j<n2)) ? uj : 1.0f;
        }
        float ag = scal[S_AG], wg = scal[S_WG];
        float a1 = (1.0f-uA)*p1, a2 = (1.0f-uB)*p2;
        float w1 = wg*(ag*a1 + (1.0f-ag)*wcs[n1]);
        float w2 = wg*(ag*a2 + (1.0f-ag)*wcs[n2]);
        wws[n1]=w1; wws[n2]=w2;
        float s = wsum64(w1+w2);
        if (lane==0) scal[S_WSUM]=s;
      }
      __syncthreads();

      // ---- C3: M update (w0-7) ∥ L update (w8-15) ----
      if (wid < 8){
        #pragma unroll
        for (int i=0;i<16;i++){
          int el = tid + i*512, n = el>>6, d = el&63;
          float w = wws[n];
          Ms[n*65+d] = Ms[n*65+d]*(1.0f - w*ers[d]) + w*wvs[d];
        }
      } else {
        int tt2 = tid - 512;
        #pragma unroll
        for (int i=0;i<32;i++){
          int el = tt2 + i*512, li = el>>7, lj = el&127;
          float v = (li==lj) ? 0.0f
                  : (1.0f - wws[li] - wws[lj])*Ls[li*129+lj] + wws[li]*prc[lj];
          Ls[li*129+lj] = v;
        }
      }
      __syncthreads();

      // ---- C4: rcs per-head (w0-3, mnorm fused) ∥ fwd/bwd (w8-15) ∥ prec (w4) ----
      if (wid < 4){
        const int r = wid;
        int n1 = lane, n2 = lane + 64;
        float d1=0.f, d2=0.f, kn=0.f, q1=0.f, q2=0.f;
        #pragma unroll 8
        for (int d=0; d<WD; ++d){
          float rk = ifcl[OFF_RK + r*WD + d];
          float m1 = Ms[n1*65+d], m2 = Ms[n2*65+d];
          d1 += rk*m1; d2 += rk*m2;
          kn += rk*rk; q1 += m1*m1; q2 += m2*m2;
        }
        float rstr = 1.0f + sofp(ifcl[OFF_RSTR+r]);
        float knr = sqrtf(kn);
        float s1 = d1/(knr*sqrtf(q1)+EPSV)*rstr;
        float s2 = d2/(knr*sqrtf(q2)+EPSV)*rstr;
        float mx = wmax64(fmaxf(s1,s2));
        float e1 = expf(s1-mx), e2 = expf(s2-mx);
        float sum = wsum64(e1+e2);
        rcs[r*NN+n1] = e1/sum; rcs[r*NN+n2] = e2/sum;
      } else if (wid >= 8){
        int idx = tid - 512, r = idx>>7, i = idx&127;
        float f=0.f, bw=0.f;
        const float* rwr = rws + r*NN;
        #pragma unroll 4
        for (int j=0;j<NN;j++){
          float rv = rwr[j];
          f  += Ls[i*129+j]*rv;
          bw += Ls[j*129+i]*rv;
        }
        fwds[idx]=f; bwds[idx]=bw;
      } else if (wid == 4){
        float wsm = scal[S_WSUM];
        prc[lane]    = (1.0f-wsm)*prc[lane]    + wws[lane];
        prc[lane+64] = (1.0f-wsm)*prc[lane+64] + wws[lane+64];
      }
      __syncthreads();

      // ---- C5: rw update ----
      if (tid < RR*NN){
        int r = tid>>7;
        rws[tid] = scal[S_BM+r]*bwds[tid] + scal[S_CM+r]*rcs[tid] + scal[S_FM+r]*fwds[tid];
      }
      __syncthreads();

      // ---- C6: reads = rw @ M -> greads ----
      if (tid < RR*WD){
        int r = tid>>6, d = tid&63;
        float s=0.f;
        #pragma unroll 8
        for (int n=0;n<NN;n++) s += rws[r*NN+n]*Ms[n*65+d];
        gstore(&greads[tid*32 + g], s);
      }
      setflag(fC, g, (unsigned)(t+1));
    }
  }
}

extern "C" void kernel_launch(void* const* d_in, const int* in_sizes, int n_in,
                              void* d_out, int out_size, void* d_ws, size_t ws_size,
                              hipStream_t stream)
{
  const float* inputs=(const float*)d_in[0];
  const float* Wx0   =(const float*)d_in[1];
  const float* Wh0   =(const float*)d_in[2];
  const float* b0    =(const float*)d_in[3];
  const float* Wx1   =(const float*)d_in[4];
  const float* Wh1   =(const float*)d_in[5];
  const float* b1    =(const float*)d_in[6];
  const float* Wif   =(const float*)d_in[7];
  const float* bif   =(const float*)d_in[8];
  const float* Wout  =(const float*)d_in[9];
  const float* bout  =(const float*)d_in[10];
  float* out = (float*)d_out;
  float* ws  = (float*)d_ws;

  hipMemsetAsync(ws, 0, W_END * sizeof(float), stream);

  hipFuncSetAttribute((const void*)dnc_coop9,
                      hipFuncAttributeMaxDynamicSharedMemorySize, SMEM_BYTES);

  void* args[] = { (void*)&inputs, (void*)&Wx0, (void*)&Wh0, (void*)&b0,
                   (void*)&Wx1, (void*)&Wh1, (void*)&b1, (void*)&Wif,
                   (void*)&bif, (void*)&Wout, (void*)&bout, (void*)&out,
                   (void*)&ws };
  hipLaunchCooperativeKernel((void*)dnc_coop9, dim3(NBLK), dim3(1024),
                             args, SMEM_BYTES, stream);
}